// Round 1
// baseline (796.661 us; speedup 1.0000x reference)
//
#include <hip/hip_runtime.h>
#include <hip/hip_bf16.h>

// db4 filters (float32, matching pywt 'db4')
__constant__ float c_dec_lo[8] = {
    -0.010597401784997278f, 0.032883011666982945f, 0.030841381835986965f,
    -0.18703481171888114f, -0.02798376941698385f, 0.6308807679295904f,
    0.7148465705525415f, 0.23037781330885523f};
__constant__ float c_dec_hi[8] = {
    -0.23037781330885523f, 0.7148465705525415f, -0.6308807679295904f,
    -0.02798376941698385f, 0.18703481171888114f, 0.030841381835986965f,
    -0.032883011666982945f, -0.010597401784997278f};
__constant__ float c_rec_lo[8] = {
    0.23037781330885523f, 0.7148465705525415f, 0.6308807679295904f,
    -0.02798376941698385f, -0.18703481171888114f, 0.030841381835986965f,
    0.032883011666982945f, -0.010597401784997278f};
__constant__ float c_rec_hi[8] = {
    -0.010597401784997278f, -0.032883011666982945f, 0.030841381835986965f,
    0.18703481171888114f, -0.02798376941698385f, -0.6308807679295904f,
    0.7148465705525415f, -0.23037781330885523f};

__device__ __forceinline__ float soft_enh(float v, float th) {
    float e = 1.5f * v;
    float a = fabsf(e) - th;
    return a > 0.0f ? copysignf(a, e) : 0.0f;
}

// DWT along last (contiguous) axis. x: (rows, S) -> lo,hi: (rows, Nc)
__global__ void row_dwt_k(const float* __restrict__ x, float* __restrict__ lo,
                          float* __restrict__ hi, int S, int Nc, long total) {
    long idx = (long)blockIdx.x * blockDim.x + threadIdx.x;
    if (idx >= total) return;
    int j = (int)(idx % Nc);
    long r = idx / Nc;
    const float* xr = x + r * (long)S;
    float alo = 0.f, ahi = 0.f;
    int p0 = 2 * j + 1;
#pragma unroll
    for (int t = 0; t < 8; ++t) {
        int p = p0 - t;
        p = (p < 0) ? (-1 - p) : p;
        p = (p >= S) ? (2 * S - 1 - p) : p;
        float v = xr[p];
        alo = fmaf(c_dec_lo[t], v, alo);
        ahi = fmaf(c_dec_hi[t], v, ahi);
    }
    lo[idx] = alo;
    hi[idx] = ahi;
}

// DWT along middle axis. x: (M, H, W) -> lo,hi: (M, Hc, W), coalesced in w.
__global__ void col_dwt_k(const float* __restrict__ x, float* __restrict__ lo,
                          float* __restrict__ hi, int H, int Hc, int W, long total) {
    long idx = (long)blockIdx.x * blockDim.x + threadIdx.x;
    if (idx >= total) return;
    int w = (int)(idx % W);
    long tmp = idx / W;
    int j = (int)(tmp % Hc);
    int m = (int)(tmp / Hc);
    const float* xm = x + (long)m * H * W;
    float alo = 0.f, ahi = 0.f;
    int p0 = 2 * j + 1;
#pragma unroll
    for (int t = 0; t < 8; ++t) {
        int p = p0 - t;
        p = (p < 0) ? (-1 - p) : p;
        p = (p >= H) ? (2 * H - 1 - p) : p;
        float v = xm[(long)p * W + w];
        alo = fmaf(c_dec_lo[t], v, alo);
        ahi = fmaf(c_dec_hi[t], v, ahi);
    }
    lo[idx] = alo;   // output layout (M,Hc,W) == flat idx
    hi[idx] = ahi;
}

// Per-image-band max|x| -> th[m] = 0.2*(1.5*max). One block per band.
__global__ void band_maxabs_k(const float* __restrict__ x, float* __restrict__ th, int n) {
    int m = blockIdx.x;
    const float* xm = x + (long)m * n;
    float mx = 0.f;
    for (int i = threadIdx.x; i < n; i += blockDim.x) mx = fmaxf(mx, fabsf(xm[i]));
#pragma unroll
    for (int off = 32; off > 0; off >>= 1) mx = fmaxf(mx, __shfl_down(mx, off));
    __shared__ float smax[8];
    int wave = threadIdx.x >> 6, lane = threadIdx.x & 63;
    if (lane == 0) smax[wave] = mx;
    __syncthreads();
    if (threadIdx.x == 0) {
        float r = smax[0];
        int nw = blockDim.x >> 6;
        for (int i = 1; i < nw; ++i) r = fmaxf(r, smax[i]);
        th[m] = 0.2f * (1.5f * r);
    }
}

// IDWT along middle axis with optional fused soft-enhance on either input.
// lo,hi: (M, n, W) -> out: (M, Hout=2n-6, W). All taps in-bounds (n>=4).
__global__ void col_idwt_k(const float* __restrict__ lo, const float* __restrict__ hi,
                           const float* __restrict__ th_lo, const float* __restrict__ th_hi,
                           float* __restrict__ out, int n, int Hout, int W, long total) {
    long idx = (long)blockIdx.x * blockDim.x + threadIdx.x;
    if (idx >= total) return;
    int w = (int)(idx % W);
    long tmp = idx / W;
    int i = (int)(tmp % Hout);
    int m = (int)(tmp / Hout);
    const float* lom = lo + (long)m * n * W;
    const float* him = hi + (long)m * n * W;
    const bool do_lo = (th_lo != nullptr), do_hi = (th_hi != nullptr);
    float tl = do_lo ? th_lo[m] : 0.f;
    float tt = do_hi ? th_hi[m] : 0.f;
    int t0 = i & 1;
    float acc = 0.f;
#pragma unroll
    for (int s = 0; s < 4; ++s) {
        int t = t0 + 2 * s;
        int j = (i + 6 - t) >> 1;
        float lv = lom[(long)j * W + w];
        float hv = him[(long)j * W + w];
        if (do_lo) lv = soft_enh(lv, tl);
        if (do_hi) hv = soft_enh(hv, tt);
        acc = fmaf(c_rec_lo[t], lv, acc);
        acc = fmaf(c_rec_hi[t], hv, acc);
    }
    out[idx] = acc;
}

// IDWT along last axis. lo,hi: (rows, n) -> out: (rows, Sout=2n-6)
__global__ void row_idwt_k(const float* __restrict__ lo, const float* __restrict__ hi,
                           float* __restrict__ out, int n, int Sout, long total) {
    long idx = (long)blockIdx.x * blockDim.x + threadIdx.x;
    if (idx >= total) return;
    int i = (int)(idx % Sout);
    long r = idx / Sout;
    const float* lor = lo + r * (long)n;
    const float* hir = hi + r * (long)n;
    int t0 = i & 1;
    float acc = 0.f;
#pragma unroll
    for (int s = 0; s < 4; ++s) {
        int t = t0 + 2 * s;
        int j = (i + 6 - t) >> 1;
        acc = fmaf(c_rec_lo[t], lor[j], acc);
        acc = fmaf(c_rec_hi[t], hir[j], acc);
    }
    out[idx] = acc;
}

extern "C" void kernel_launch(void* const* d_in, const int* in_sizes, int n_in,
                              void* d_out, int out_size, void* d_ws, size_t ws_size,
                              hipStream_t stream) {
    const float* x = (const float*)d_in[0];
    float* out = (float*)d_out;
    float* ws = (float*)d_ws;

    const int M = 96, S1 = 510, N1 = 258, S2 = 258, N2 = 132;
    const long S_row1 = (long)M * S1 * N1;  // 12,631,680
    const long S_l1   = (long)M * N1 * N1;  // 6,390,144
    const long S_row2 = (long)M * S2 * N2;  // 3,269,376
    const long S_l2   = (long)M * N2 * N2;  // 1,672,704

    // Lifetime-aliased layout (~194 MiB):
    float* C_ = ws;              // h1 (da)        [steps 2..12]
    float* D_ = C_ + S_l1;       // v1 (ad)        [3..13]
    float* E_ = D_ + S_l1;       // d1 (dd)        [3..13]
    float* F_ = E_ + S_l1;       // aa [2..5] then a1r [11..12]
    float* A_ = F_ + S_l1;       // rowlo1 [1..2]; a2/h2/v2/d2 [6..10]; lo [12..14]
    float* B_ = A_ + S_row1;     // rowhi1 [1..3]; rowlo2/rowhi2/lo1t/hi1t [5..11]; hi [13..14]
    float* TH = B_ + S_row1;     // 6*96 thresholds

    long need_floats = 4 * S_l1 + 2 * S_row1 + 576;
    if (ws_size < (size_t)need_floats * sizeof(float)) return;  // fail loudly

    float* I_ = A_;              // a2
    float* J_ = I_ + S_l2;       // h2
    float* K_ = J_ + S_l2;       // v2
    float* Lb = K_ + S_l2;       // d2
    float* G_ = B_;              // rowlo2 / lo1t
    float* H_ = G_ + S_row2;     // rowhi2 / hi1t

    float* th_h1 = TH, *th_v1 = TH + 96, *th_d1 = TH + 192;
    float* th_h2 = TH + 288, *th_v2 = TH + 384, *th_d2 = TH + 480;

    const int BLK = 256;
    auto nb = [&](long t) { return (unsigned)((t + BLK - 1) / BLK); };

    // ---- Level 1 decomposition ----
    long t_row1 = S_row1;
    row_dwt_k<<<nb(t_row1), BLK, 0, stream>>>(x, A_, B_, S1, N1, t_row1);
    long t_l1 = S_l1;
    col_dwt_k<<<nb(t_l1), BLK, 0, stream>>>(A_, F_, C_, S1, N1, N1, t_l1);  // aa, h1
    col_dwt_k<<<nb(t_l1), BLK, 0, stream>>>(B_, D_, E_, S1, N1, N1, t_l1);  // v1, d1
    band_maxabs_k<<<M, 256, 0, stream>>>(C_, th_h1, N1 * N1);
    band_maxabs_k<<<M, 256, 0, stream>>>(D_, th_v1, N1 * N1);
    band_maxabs_k<<<M, 256, 0, stream>>>(E_, th_d1, N1 * N1);

    // ---- Level 2 decomposition (on aa) ----
    long t_row2 = S_row2;
    row_dwt_k<<<nb(t_row2), BLK, 0, stream>>>(F_, G_, H_, S2, N2, t_row2);
    long t_l2 = S_l2;
    col_dwt_k<<<nb(t_l2), BLK, 0, stream>>>(G_, I_, J_, S2, N2, N2, t_l2);  // a2, h2
    col_dwt_k<<<nb(t_l2), BLK, 0, stream>>>(H_, K_, Lb, S2, N2, N2, t_l2);  // v2, d2
    band_maxabs_k<<<M, 256, 0, stream>>>(J_, th_h2, N2 * N2);
    band_maxabs_k<<<M, 256, 0, stream>>>(K_, th_v2, N2 * N2);
    band_maxabs_k<<<M, 256, 0, stream>>>(Lb, th_d2, N2 * N2);

    // ---- Level 2 reconstruction (soft-enhance fused on detail loads) ----
    col_idwt_k<<<nb(t_row2), BLK, 0, stream>>>(I_, J_, nullptr, th_h2, G_, N2, S2, N2, t_row2);
    col_idwt_k<<<nb(t_row2), BLK, 0, stream>>>(K_, Lb, th_v2, th_d2, H_, N2, S2, N2, t_row2);
    long t_a1 = S_l1;
    row_idwt_k<<<nb(t_a1), BLK, 0, stream>>>(G_, H_, F_, N2, S2, t_a1);     // a1r

    // ---- Level 1 reconstruction ----
    col_idwt_k<<<nb(t_row1), BLK, 0, stream>>>(F_, C_, nullptr, th_h1, A_, N1, S1, N1, t_row1);
    col_idwt_k<<<nb(t_row1), BLK, 0, stream>>>(D_, E_, th_v1, th_d1, B_, N1, S1, N1, t_row1);
    long t_out = (long)M * S1 * S1;
    row_idwt_k<<<nb(t_out), BLK, 0, stream>>>(A_, B_, out, N1, S1, t_out);
}

// Round 2
// 422.017 us; speedup vs baseline: 1.8877x; 1.8877x over previous
//
#include <hip/hip_runtime.h>

// db4 filters (float32, matching pywt 'db4')
__constant__ float c_dec_lo[8] = {
    -0.010597401784997278f, 0.032883011666982945f, 0.030841381835986965f,
    -0.18703481171888114f, -0.02798376941698385f, 0.6308807679295904f,
    0.7148465705525415f, 0.23037781330885523f};
__constant__ float c_dec_hi[8] = {
    -0.23037781330885523f, 0.7148465705525415f, -0.6308807679295904f,
    -0.02798376941698385f, 0.18703481171888114f, 0.030841381835986965f,
    -0.032883011666982945f, -0.010597401784997278f};
__constant__ float c_rec_lo[8] = {
    0.23037781330885523f, 0.7148465705525415f, 0.6308807679295904f,
    -0.02798376941698385f, -0.18703481171888114f, 0.030841381835986965f,
    0.032883011666982945f, -0.010597401784997278f};
__constant__ float c_rec_hi[8] = {
    -0.010597401784997278f, -0.032883011666982945f, 0.030841381835986965f,
    0.18703481171888114f, -0.02798376941698385f, -0.6308807679295904f,
    0.7148465705525415f, -0.23037781330885523f};

__device__ __forceinline__ float soft_enh(float v, float th) {
    float e = 1.5f * v;
    float a = fabsf(e) - th;
    return a > 0.0f ? copysignf(a, e) : 0.0f;
}

#define TB 32     // dwt output tile (per band)
#define DIN 70    // 2*TB+6 input tile
#define TO 64     // idwt output tile
#define CN 35     // TO/2+3 coefficient tile
#define CNP 36    // padded

// Fused 2D DWT: x (M,S,S) -> aa,da,ad,dd (M,Nc,Nc); block = one 32x32 coef tile.
// Also folds per-image max|band| for da/ad/dd via atomicMax on float bits.
__global__ __launch_bounds__(256) void fused_dwt2_k(
    const float* __restrict__ x, int S, int Nc, int tiles,
    float* __restrict__ aa, float* __restrict__ da,
    float* __restrict__ ad, float* __restrict__ dd,
    unsigned* __restrict__ mx_da, unsigned* __restrict__ mx_ad,
    unsigned* __restrict__ mx_dd)
{
    int b = blockIdx.x;
    int tx = b % tiles, ty = (b / tiles) % tiles, m = b / (tiles * tiles);
    int jh0 = ty * TB, jw0 = tx * TB;
    const float* xm = x + (size_t)m * S * S;

    __shared__ float X[DIN][DIN + 1];
    __shared__ float RL[DIN][TB];
    __shared__ float RH[DIN][TB];

    int tid = threadIdx.x;
    // stage 1: load input tile with symmetric reflection
    int r0 = 2 * jh0 - 6, c0 = 2 * jw0 - 6;
    for (int e = tid; e < DIN * DIN; e += 256) {
        int r = e / DIN, c = e % DIN;
        int pr = r0 + r; pr = pr < 0 ? -1 - pr : pr; pr = pr >= S ? 2 * S - 1 - pr : pr;
        int pc = c0 + c; pc = pc < 0 ? -1 - pc : pc; pc = pc >= S ? 2 * S - 1 - pc : pc;
        X[r][c] = xm[(size_t)pr * S + pc];
    }
    __syncthreads();
    // stage 2: row dwt (along cols of X) -> RL, RH  [DIN rows x TB cols]
    for (int e = tid; e < DIN * TB; e += 256) {
        int r = e / TB, jj = e % TB;
        float alo = 0.f, ahi = 0.f;
#pragma unroll
        for (int t = 0; t < 8; ++t) {
            float v = X[r][2 * jj + 7 - t];
            alo = fmaf(c_dec_lo[t], v, alo);
            ahi = fmaf(c_dec_hi[t], v, ahi);
        }
        RL[r][jj] = alo; RH[r][jj] = ahi;
    }
    __syncthreads();
    // stage 3: col dwt -> 4 bands, fused block max of details
    float mh = 0.f, mv = 0.f, md = 0.f;
    for (int e = tid; e < TB * TB; e += 256) {
        int ii = e / TB, jj = e % TB;
        float vaa = 0.f, vda = 0.f, vad = 0.f, vdd = 0.f;
#pragma unroll
        for (int t = 0; t < 8; ++t) {
            float l = RL[2 * ii + 7 - t][jj];
            float h = RH[2 * ii + 7 - t][jj];
            vaa = fmaf(c_dec_lo[t], l, vaa);
            vda = fmaf(c_dec_hi[t], l, vda);
            vad = fmaf(c_dec_lo[t], h, vad);
            vdd = fmaf(c_dec_hi[t], h, vdd);
        }
        int jh = jh0 + ii, jw = jw0 + jj;
        if (jh < Nc && jw < Nc) {
            size_t o = ((size_t)m * Nc + jh) * Nc + jw;
            aa[o] = vaa; da[o] = vda; ad[o] = vad; dd[o] = vdd;
            mh = fmaxf(mh, fabsf(vda));
            mv = fmaxf(mv, fabsf(vad));
            md = fmaxf(md, fabsf(vdd));
        }
    }
#pragma unroll
    for (int off = 32; off; off >>= 1) {
        mh = fmaxf(mh, __shfl_down(mh, off));
        mv = fmaxf(mv, __shfl_down(mv, off));
        md = fmaxf(md, __shfl_down(md, off));
    }
    __shared__ float sm[3][4];
    int wv = tid >> 6, ln = tid & 63;
    if (ln == 0) { sm[0][wv] = mh; sm[1][wv] = mv; sm[2][wv] = md; }
    __syncthreads();
    if (tid == 0) {
        float a = fmaxf(fmaxf(sm[0][0], sm[0][1]), fmaxf(sm[0][2], sm[0][3]));
        float bb = fmaxf(fmaxf(sm[1][0], sm[1][1]), fmaxf(sm[1][2], sm[1][3]));
        float c = fmaxf(fmaxf(sm[2][0], sm[2][1]), fmaxf(sm[2][2], sm[2][3]));
        atomicMax(mx_da + m, __float_as_uint(a));
        atomicMax(mx_ad + m, __float_as_uint(bb));
        atomicMax(mx_dd + m, __float_as_uint(c));
    }
}

// Fused 2D IDWT: a,h,v,d (M,n,n) -> out (M,Ho,Ho), Ho=2n-6.
// Soft-enhance fused on h/v/d loads (a passes through).
__global__ __launch_bounds__(256) void fused_idwt2_k(
    const float* __restrict__ a, const float* __restrict__ h,
    const float* __restrict__ v, const float* __restrict__ d,
    const unsigned* __restrict__ mxh, const unsigned* __restrict__ mxv,
    const unsigned* __restrict__ mxd,
    int n, int Ho, int tiles, float* __restrict__ out)
{
    int b = blockIdx.x;
    int tx = b % tiles, ty = (b / tiles) % tiles, m = b / (tiles * tiles);
    int i0 = ty * TO, u0 = tx * TO;
    int jr0 = i0 >> 1, jc0 = u0 >> 1;

    __shared__ float As[CN][CNP], Hs[CN][CNP], Vs[CN][CNP], Ds[CN][CNP];
    __shared__ float LO[TO][CNP], HI[TO][CNP];

    int tid = threadIdx.x;
    float th_h = 0.2f * (1.5f * __uint_as_float(mxh[m]));
    float th_v = 0.2f * (1.5f * __uint_as_float(mxv[m]));
    float th_d = 0.2f * (1.5f * __uint_as_float(mxd[m]));
    const float* am = a + (size_t)m * n * n;
    const float* hm = h + (size_t)m * n * n;
    const float* vm = v + (size_t)m * n * n;
    const float* dm = d + (size_t)m * n * n;

    // stage A: load coef tiles, soft-enhance details
    for (int e = tid; e < CN * CN; e += 256) {
        int r = e / CN, c = e % CN;
        int jr = jr0 + r; if (jr > n - 1) jr = n - 1;
        int jc = jc0 + c; if (jc > n - 1) jc = n - 1;
        size_t o = (size_t)jr * n + jc;
        As[r][c] = am[o];
        Hs[r][c] = soft_enh(hm[o], th_h);
        Vs[r][c] = soft_enh(vm[o], th_v);
        Ds[r][c] = soft_enh(dm[o], th_d);
    }
    __syncthreads();
    // stage B: column idwt -> LO (from a,h), HI (from v,d)
    for (int e = tid; e < TO * CN; e += 256) {
        int il = e / CN, jc = e % CN;
        int t0 = il & 1;
        float lo = 0.f, hi = 0.f;
#pragma unroll
        for (int s = 0; s < 4; ++s) {
            int t = t0 + 2 * s;
            int r = (il + 6 - t) >> 1;
            lo = fmaf(c_rec_lo[t], As[r][jc], lo);
            lo = fmaf(c_rec_hi[t], Hs[r][jc], lo);
            hi = fmaf(c_rec_lo[t], Vs[r][jc], hi);
            hi = fmaf(c_rec_hi[t], Ds[r][jc], hi);
        }
        LO[il][jc] = lo; HI[il][jc] = hi;
    }
    __syncthreads();
    // stage C: row idwt -> out tile
    for (int e = tid; e < TO * TO; e += 256) {
        int il = e >> 6, ul = e & 63;
        int t0 = ul & 1;
        float acc = 0.f;
#pragma unroll
        for (int s = 0; s < 4; ++s) {
            int t = t0 + 2 * s;
            int c = (ul + 6 - t) >> 1;
            acc = fmaf(c_rec_lo[t], LO[il][c], acc);
            acc = fmaf(c_rec_hi[t], HI[il][c], acc);
        }
        int gi = i0 + il, gu = u0 + ul;
        if (gi < Ho && gu < Ho)
            out[((size_t)m * Ho + gi) * Ho + gu] = acc;
    }
}

extern "C" void kernel_launch(void* const* d_in, const int* in_sizes, int n_in,
                              void* d_out, int out_size, void* d_ws, size_t ws_size,
                              hipStream_t stream) {
    const float* x = (const float*)d_in[0];
    float* out = (float*)d_out;
    float* ws = (float*)d_ws;

    const int M = 96, S1 = 510, N1 = 258, N2 = 132;
    const long S_l1 = (long)M * N1 * N1;  // 6,390,144
    const long S_l2 = (long)M * N2 * N2;  // 1,672,704

    float* aa1 = ws;
    float* h1  = aa1 + S_l1;
    float* v1  = h1 + S_l1;
    float* d1  = v1 + S_l1;
    float* a1r = d1 + S_l1;
    float* a2  = a1r + S_l1;
    float* h2  = a2 + S_l2;
    float* v2  = h2 + S_l2;
    float* d2  = v2 + S_l2;
    unsigned* th = (unsigned*)(d2 + S_l2);   // 6*96 uints

    long need = 5 * S_l1 + 4 * S_l2 + 576;
    if (ws_size < (size_t)need * sizeof(float)) return;

    unsigned *th_h1 = th, *th_v1 = th + 96, *th_d1 = th + 192;
    unsigned *th_h2 = th + 288, *th_v2 = th + 384, *th_d2 = th + 480;

    hipMemsetAsync(th, 0, 576 * sizeof(unsigned), stream);

    // Level 1 decomposition: x(510) -> bands(258). 9x9 tiles per image.
    fused_dwt2_k<<<9 * 9 * M, 256, 0, stream>>>(x, S1, N1, 9, aa1, h1, v1, d1,
                                                th_h1, th_v1, th_d1);
    // Level 2 decomposition: aa1(258) -> bands(132). 5x5 tiles.
    fused_dwt2_k<<<5 * 5 * M, 256, 0, stream>>>(aa1, N1, N2, 5, a2, h2, v2, d2,
                                                th_h2, th_v2, th_d2);
    // Level 2 reconstruction: (132) -> a1r(258). ceil(258/64)=5 tiles.
    fused_idwt2_k<<<5 * 5 * M, 256, 0, stream>>>(a2, h2, v2, d2, th_h2, th_v2, th_d2,
                                                 N2, N1, 5, a1r);
    // Level 1 reconstruction: (258) -> out(510). ceil(510/64)=8 tiles.
    fused_idwt2_k<<<8 * 8 * M, 256, 0, stream>>>(a1r, h1, v1, d1, th_h1, th_v1, th_d1,
                                                 N1, S1, 8, out);
}

// Round 3
// 366.580 us; speedup vs baseline: 2.1732x; 1.1512x over previous
//
#include <hip/hip_runtime.h>

// db4 filters (float32, matching pywt 'db4')
__constant__ float c_dec_lo[8] = {
    -0.010597401784997278f, 0.032883011666982945f, 0.030841381835986965f,
    -0.18703481171888114f, -0.02798376941698385f, 0.6308807679295904f,
    0.7148465705525415f, 0.23037781330885523f};
__constant__ float c_dec_hi[8] = {
    -0.23037781330885523f, 0.7148465705525415f, -0.6308807679295904f,
    -0.02798376941698385f, 0.18703481171888114f, 0.030841381835986965f,
    -0.032883011666982945f, -0.010597401784997278f};
__constant__ float c_rec_lo[8] = {
    0.23037781330885523f, 0.7148465705525415f, 0.6308807679295904f,
    -0.02798376941698385f, -0.18703481171888114f, 0.030841381835986965f,
    0.032883011666982945f, -0.010597401784997278f};
__constant__ float c_rec_hi[8] = {
    -0.010597401784997278f, -0.032883011666982945f, 0.030841381835986965f,
    0.18703481171888114f, -0.02798376941698385f, -0.6308807679295904f,
    0.7148465705525415f, -0.23037781330885523f};

__device__ __forceinline__ float soft_enh(float v, float th) {
    float e = 1.5f * v;
    float a = fabsf(e) - th;
    return a > 0.0f ? copysignf(a, e) : 0.0f;
}

#define TB 32     // dwt output tile (per band)
#define TO 64     // idwt output tile

// Fused 2D DWT, single-LDS-buffer variant. Row-DWT computed straight from
// global (L1/L2 absorb the stride-2 window overlap) into RB, one barrier,
// then col-DWT to the 4 bands + fused per-image max|detail|.
// RB: lo at [r][jj], hi at [r][32+jj]; row stride 65 -> <=2-way banks.
__global__ __launch_bounds__(256, 8) void fused_dwt2_k(
    const float* __restrict__ x, int S, int Nc, int tiles,
    float* __restrict__ aa, float* __restrict__ da,
    float* __restrict__ ad, float* __restrict__ dd,
    unsigned* __restrict__ mx_da, unsigned* __restrict__ mx_ad,
    unsigned* __restrict__ mx_dd)
{
    int b = blockIdx.x;
    int tx = b % tiles, ty = (b / tiles) % tiles, m = b / (tiles * tiles);
    int jh0 = ty * TB, jw0 = tx * TB;
    int r0 = 2 * jh0 - 6, c0 = 2 * jw0 - 6;
    const float* xm = x + (size_t)m * S * S;

    __shared__ float RB[70][65];   // 18,200 B

    int tid = threadIdx.x;
    bool interior = (r0 >= 0) & (r0 + 69 < S) & (c0 >= 0) & (c0 + 69 < S);

    if (interior) {
        for (int e = tid; e < 70 * 32; e += 256) {
            int r = e >> 5, jj = e & 31;
            const float* row = xm + (size_t)(r0 + r) * S + (c0 + 2 * jj);
            float alo = 0.f, ahi = 0.f;
#pragma unroll
            for (int t = 0; t < 8; ++t) {
                float v = row[7 - t];
                alo = fmaf(c_dec_lo[t], v, alo);
                ahi = fmaf(c_dec_hi[t], v, ahi);
            }
            RB[r][jj] = alo; RB[r][32 + jj] = ahi;
        }
    } else {
        for (int e = tid; e < 70 * 32; e += 256) {
            int r = e >> 5, jj = e & 31;
            int pr = r0 + r;
            pr = pr < 0 ? -1 - pr : pr;
            pr = pr >= S ? 2 * S - 1 - pr : pr;
            const float* row = xm + (size_t)pr * S;
            int pb = c0 + 2 * jj;
            float alo = 0.f, ahi = 0.f;
#pragma unroll
            for (int t = 0; t < 8; ++t) {
                int p = pb + 7 - t;
                p = p < 0 ? -1 - p : p;
                p = p >= S ? 2 * S - 1 - p : p;
                float v = row[p];
                alo = fmaf(c_dec_lo[t], v, alo);
                ahi = fmaf(c_dec_hi[t], v, ahi);
            }
            RB[r][jj] = alo; RB[r][32 + jj] = ahi;
        }
    }
    __syncthreads();

    // col dwt -> 4 bands + fused block max of details
    float mh = 0.f, mv = 0.f, md = 0.f;
    for (int e = tid; e < TB * TB; e += 256) {
        int ii = e >> 5, jj = e & 31;
        float vaa = 0.f, vda = 0.f, vad = 0.f, vdd = 0.f;
#pragma unroll
        for (int t = 0; t < 8; ++t) {
            float l = RB[2 * ii + 7 - t][jj];
            float h = RB[2 * ii + 7 - t][32 + jj];
            vaa = fmaf(c_dec_lo[t], l, vaa);
            vda = fmaf(c_dec_hi[t], l, vda);
            vad = fmaf(c_dec_lo[t], h, vad);
            vdd = fmaf(c_dec_hi[t], h, vdd);
        }
        int jh = jh0 + ii, jw = jw0 + jj;
        if (jh < Nc && jw < Nc) {
            size_t o = ((size_t)m * Nc + jh) * Nc + jw;
            aa[o] = vaa; da[o] = vda; ad[o] = vad; dd[o] = vdd;
            mh = fmaxf(mh, fabsf(vda));
            mv = fmaxf(mv, fabsf(vad));
            md = fmaxf(md, fabsf(vdd));
        }
    }
#pragma unroll
    for (int off = 32; off; off >>= 1) {
        mh = fmaxf(mh, __shfl_down(mh, off));
        mv = fmaxf(mv, __shfl_down(mv, off));
        md = fmaxf(md, __shfl_down(md, off));
    }
    __shared__ float sm[3][4];
    int wv = tid >> 6, ln = tid & 63;
    if (ln == 0) { sm[0][wv] = mh; sm[1][wv] = mv; sm[2][wv] = md; }
    __syncthreads();
    if (tid == 0) {
        float A = fmaxf(fmaxf(sm[0][0], sm[0][1]), fmaxf(sm[0][2], sm[0][3]));
        float B = fmaxf(fmaxf(sm[1][0], sm[1][1]), fmaxf(sm[1][2], sm[1][3]));
        float C = fmaxf(fmaxf(sm[2][0], sm[2][1]), fmaxf(sm[2][2], sm[2][3]));
        atomicMax(mx_da + m, __float_as_uint(A));
        atomicMax(mx_ad + m, __float_as_uint(B));
        atomicMax(mx_dd + m, __float_as_uint(C));
    }
}

// Fused 2D IDWT, single-LDS-buffer variant. Column-IDWT computed straight
// from global into 16 register accumulators (8-row output group per task,
// coef rows shared within the group), soft-enhance fused at load; one
// barrier; then row-IDWT from LH. LH: lo at [il][jc], hi at [il][35+jc].
__global__ __launch_bounds__(256, 6) void fused_idwt2_k(
    const float* __restrict__ a, const float* __restrict__ h,
    const float* __restrict__ v, const float* __restrict__ d,
    const unsigned* __restrict__ mxh, const unsigned* __restrict__ mxv,
    const unsigned* __restrict__ mxd,
    int n, int Ho, int tiles, float* __restrict__ out)
{
    int b = blockIdx.x;
    int tx = b % tiles, ty = (b / tiles) % tiles, m = b / (tiles * tiles);
    int i0 = ty * TO, u0 = tx * TO;
    int jr0 = i0 >> 1, jc0 = u0 >> 1;

    __shared__ float LH[TO][71];   // 18,176 B

    int tid = threadIdx.x;
    float th_h = 0.2f * (1.5f * __uint_as_float(mxh[m]));
    float th_v = 0.2f * (1.5f * __uint_as_float(mxv[m]));
    float th_d = 0.2f * (1.5f * __uint_as_float(mxd[m]));
    const float* am = a + (size_t)m * n * n;
    const float* hm = h + (size_t)m * n * n;
    const float* vm = v + (size_t)m * n * n;
    const float* dm = d + (size_t)m * n * n;

    // column idwt: 8 groups of 8 il-rows x 35 jc = 280 tasks
    for (int task = tid; task < 8 * 35; task += 256) {
        int g = task / 35, jc = task % 35;
        int jcg = jc0 + jc; if (jcg > n - 1) jcg = n - 1;
        float acc_lo[8], acc_hi[8];
#pragma unroll
        for (int k = 0; k < 8; ++k) { acc_lo[k] = 0.f; acc_hi[k] = 0.f; }
#pragma unroll
        for (int rl = 0; rl < 7; ++rl) {
            int jr = jr0 + 4 * g + rl; if (jr > n - 1) jr = n - 1;
            size_t o = (size_t)jr * n + jcg;
            float av = am[o];
            float hv = soft_enh(hm[o], th_h);
            float vv = soft_enh(vm[o], th_v);
            float dv = soft_enh(dm[o], th_d);
#pragma unroll
            for (int t = 0; t < 8; ++t) {
                int il = 2 * rl + t - 6;           // compile-time per iteration
                if (il >= 0 && il < 8) {
                    acc_lo[il] = fmaf(c_rec_lo[t], av, fmaf(c_rec_hi[t], hv, acc_lo[il]));
                    acc_hi[il] = fmaf(c_rec_lo[t], vv, fmaf(c_rec_hi[t], dv, acc_hi[il]));
                }
            }
        }
#pragma unroll
        for (int k = 0; k < 8; ++k) {
            LH[8 * g + k][jc] = acc_lo[k];
            LH[8 * g + k][35 + jc] = acc_hi[k];
        }
    }
    __syncthreads();

    // row idwt -> out tile
    for (int e = tid; e < TO * TO; e += 256) {
        int il = e >> 6, ul = e & 63;
        int t0 = ul & 1;
        float acc = 0.f;
#pragma unroll
        for (int s = 0; s < 4; ++s) {
            int t = t0 + 2 * s;
            int c = (ul + 6 - t) >> 1;
            acc = fmaf(c_rec_lo[t], LH[il][c], acc);
            acc = fmaf(c_rec_hi[t], LH[il][35 + c], acc);
        }
        int gi = i0 + il, gu = u0 + ul;
        if (gi < Ho && gu < Ho)
            out[((size_t)m * Ho + gi) * Ho + gu] = acc;
    }
}

extern "C" void kernel_launch(void* const* d_in, const int* in_sizes, int n_in,
                              void* d_out, int out_size, void* d_ws, size_t ws_size,
                              hipStream_t stream) {
    const float* x = (const float*)d_in[0];
    float* out = (float*)d_out;
    float* ws = (float*)d_ws;

    const int M = 96, S1 = 510, N1 = 258, N2 = 132;
    const long S_l1 = (long)M * N1 * N1;
    const long S_l2 = (long)M * N2 * N2;

    float* aa1 = ws;
    float* h1  = aa1 + S_l1;
    float* v1  = h1 + S_l1;
    float* d1  = v1 + S_l1;
    float* a1r = d1 + S_l1;
    float* a2  = a1r + S_l1;
    float* h2  = a2 + S_l2;
    float* v2  = h2 + S_l2;
    float* d2  = v2 + S_l2;
    unsigned* th = (unsigned*)(d2 + S_l2);   // 6*96 uints

    long need = 5 * S_l1 + 4 * S_l2 + 576;
    if (ws_size < (size_t)need * sizeof(float)) return;

    unsigned *th_h1 = th, *th_v1 = th + 96, *th_d1 = th + 192;
    unsigned *th_h2 = th + 288, *th_v2 = th + 384, *th_d2 = th + 480;

    hipMemsetAsync(th, 0, 576 * sizeof(unsigned), stream);

    // Level 1 decomposition: x(510) -> bands(258). 9x9 tiles per image.
    fused_dwt2_k<<<9 * 9 * M, 256, 0, stream>>>(x, S1, N1, 9, aa1, h1, v1, d1,
                                                th_h1, th_v1, th_d1);
    // Level 2 decomposition: aa1(258) -> bands(132). 5x5 tiles.
    fused_dwt2_k<<<5 * 5 * M, 256, 0, stream>>>(aa1, N1, N2, 5, a2, h2, v2, d2,
                                                th_h2, th_v2, th_d2);
    // Level 2 reconstruction: (132) -> a1r(258). 5x5 tiles of 64.
    fused_idwt2_k<<<5 * 5 * M, 256, 0, stream>>>(a2, h2, v2, d2, th_h2, th_v2, th_d2,
                                                 N2, N1, 5, a1r);
    // Level 1 reconstruction: (258) -> out(510). 8x8 tiles of 64.
    fused_idwt2_k<<<8 * 8 * M, 256, 0, stream>>>(a1r, h1, v1, d1, th_h1, th_v1, th_d1,
                                                 N1, S1, 8, out);
}

// Round 4
// 359.046 us; speedup vs baseline: 2.2188x; 1.0210x over previous
//
#include <hip/hip_runtime.h>

// db4 filters (float32, matching pywt 'db4')
__constant__ float c_dec_lo[8] = {
    -0.010597401784997278f, 0.032883011666982945f, 0.030841381835986965f,
    -0.18703481171888114f, -0.02798376941698385f, 0.6308807679295904f,
    0.7148465705525415f, 0.23037781330885523f};
__constant__ float c_dec_hi[8] = {
    -0.23037781330885523f, 0.7148465705525415f, -0.6308807679295904f,
    -0.02798376941698385f, 0.18703481171888114f, 0.030841381835986965f,
    -0.032883011666982945f, -0.010597401784997278f};
__constant__ float c_rec_lo[8] = {
    0.23037781330885523f, 0.7148465705525415f, 0.6308807679295904f,
    -0.02798376941698385f, -0.18703481171888114f, 0.030841381835986965f,
    0.032883011666982945f, -0.010597401784997278f};
__constant__ float c_rec_hi[8] = {
    -0.010597401784997278f, -0.032883011666982945f, 0.030841381835986965f,
    0.18703481171888114f, -0.02798376941698385f, -0.6308807679295904f,
    0.7148465705525415f, -0.23037781330885523f};

__device__ __forceinline__ float soft_enh(float v, float th) {
    float e = 1.5f * v;
    float a = fabsf(e) - th;
    return a > 0.0f ? copysignf(a, e) : 0.0f;
}

#define TB 32
#define TO 64

// Fused 2D DWT. Row-DWT: 4 outputs/thread from 16 contiguous floats (8x
// float2 loads, 8B-aligned: all offsets even). RB stride 68 -> b128-aligned
// writes, conflict-free column reads (bank=(4*row+jj)%32).
__global__ __launch_bounds__(256, 8) void fused_dwt2_k(
    const float* __restrict__ x, int S, int Nc, int tiles,
    float* __restrict__ aa, float* __restrict__ da,
    float* __restrict__ ad, float* __restrict__ dd,
    unsigned* __restrict__ mx_da, unsigned* __restrict__ mx_ad,
    unsigned* __restrict__ mx_dd)
{
    int b = blockIdx.x;
    int tx = b % tiles, ty = (b / tiles) % tiles, m = b / (tiles * tiles);
    int jh0 = ty * TB, jw0 = tx * TB;
    int r0 = 2 * jh0 - 6, c0 = 2 * jw0 - 6;
    const float* xm = x + (size_t)m * S * S;

    __shared__ float RB[70][68];   // 19,040 B

    int tid = threadIdx.x;
    bool colv = (c0 >= 0) && (c0 + 71 < S);   // vector path: cols in-bounds

    if (colv) {
        for (int e = tid; e < 560; e += 256) {
            int r = e >> 3, q = e & 7;
            int pr = r0 + r;
            pr = pr < 0 ? -1 - pr : pr;
            pr = pr >= S ? 2 * S - 1 - pr : pr;
            const float* src = xm + (size_t)pr * S + (c0 + 8 * q);
            float f[16];
#pragma unroll
            for (int i = 0; i < 8; ++i) {
                float2 v = *reinterpret_cast<const float2*>(src + 2 * i);
                f[2 * i] = v.x; f[2 * i + 1] = v.y;
            }
            float lo[4], hi[4];
#pragma unroll
            for (int i = 0; i < 4; ++i) {
                float alo = 0.f, ahi = 0.f;
#pragma unroll
                for (int t = 0; t < 8; ++t) {
                    float v = f[2 * i + 7 - t];
                    alo = fmaf(c_dec_lo[t], v, alo);
                    ahi = fmaf(c_dec_hi[t], v, ahi);
                }
                lo[i] = alo; hi[i] = ahi;
            }
            int c4 = 4 * q;
            *reinterpret_cast<float4*>(&RB[r][c4]) = make_float4(lo[0], lo[1], lo[2], lo[3]);
            *reinterpret_cast<float4*>(&RB[r][32 + c4]) = make_float4(hi[0], hi[1], hi[2], hi[3]);
        }
    } else {
        for (int e = tid; e < 70 * 32; e += 256) {
            int r = e >> 5, jj = e & 31;
            int pr = r0 + r;
            pr = pr < 0 ? -1 - pr : pr;
            pr = pr >= S ? 2 * S - 1 - pr : pr;
            const float* row = xm + (size_t)pr * S;
            int pb = c0 + 2 * jj;
            float alo = 0.f, ahi = 0.f;
#pragma unroll
            for (int t = 0; t < 8; ++t) {
                int p = pb + 7 - t;
                p = p < 0 ? -1 - p : p;
                p = p >= S ? 2 * S - 1 - p : p;
                float v = row[p];
                alo = fmaf(c_dec_lo[t], v, alo);
                ahi = fmaf(c_dec_hi[t], v, ahi);
            }
            RB[r][jj] = alo; RB[r][32 + jj] = ahi;
        }
    }
    __syncthreads();

    // col dwt: thread owns (jj, 4 consecutive ii), two register-light passes
    int jj = tid & 31, g = tid >> 5;
    int jw = jw0 + jj;
    float mh = 0.f, mv = 0.f, md = 0.f;
#pragma unroll
    for (int pass = 0; pass < 2; ++pass) {
        int rbase = 8 * g + 4 * pass;
        float L[10], H[10];
#pragma unroll
        for (int rr = 0; rr < 10; ++rr) {
            L[rr] = RB[rbase + rr][jj];
            H[rr] = RB[rbase + rr][32 + jj];
        }
#pragma unroll
        for (int k = 0; k < 2; ++k) {
            float vaa = 0.f, vda = 0.f, vad = 0.f, vdd = 0.f;
#pragma unroll
            for (int t = 0; t < 8; ++t) {
                float l = L[2 * k + 7 - t];
                float h = H[2 * k + 7 - t];
                vaa = fmaf(c_dec_lo[t], l, vaa);
                vda = fmaf(c_dec_hi[t], l, vda);
                vad = fmaf(c_dec_lo[t], h, vad);
                vdd = fmaf(c_dec_hi[t], h, vdd);
            }
            int jh = jh0 + 4 * g + 2 * pass + k;
            if (jh < Nc && jw < Nc) {
                size_t o = ((size_t)m * Nc + jh) * Nc + jw;
                aa[o] = vaa; da[o] = vda; ad[o] = vad; dd[o] = vdd;
                mh = fmaxf(mh, fabsf(vda));
                mv = fmaxf(mv, fabsf(vad));
                md = fmaxf(md, fabsf(vdd));
            }
        }
    }
#pragma unroll
    for (int off = 32; off; off >>= 1) {
        mh = fmaxf(mh, __shfl_down(mh, off));
        mv = fmaxf(mv, __shfl_down(mv, off));
        md = fmaxf(md, __shfl_down(md, off));
    }
    __shared__ float sm[3][4];
    int wv = tid >> 6, ln = tid & 63;
    if (ln == 0) { sm[0][wv] = mh; sm[1][wv] = mv; sm[2][wv] = md; }
    __syncthreads();
    if (tid == 0) {
        float A = fmaxf(fmaxf(sm[0][0], sm[0][1]), fmaxf(sm[0][2], sm[0][3]));
        float B = fmaxf(fmaxf(sm[1][0], sm[1][1]), fmaxf(sm[1][2], sm[1][3]));
        float C = fmaxf(fmaxf(sm[2][0], sm[2][1]), fmaxf(sm[2][2], sm[2][3]));
        atomicMax(mx_da + m, __float_as_uint(A));
        atomicMax(mx_ad + m, __float_as_uint(B));
        atomicMax(mx_dd + m, __float_as_uint(C));
    }
}

// Fused 2D IDWT. Column-IDWT straight from global into registers, 2 passes
// of 4 output rows (8 accumulators) to keep VGPRs under the (256,8) cap.
__global__ __launch_bounds__(256, 8) void fused_idwt2_k(
    const float* __restrict__ a, const float* __restrict__ h,
    const float* __restrict__ v, const float* __restrict__ d,
    const unsigned* __restrict__ mxh, const unsigned* __restrict__ mxv,
    const unsigned* __restrict__ mxd,
    int n, int Ho, int tiles, float* __restrict__ out)
{
    int b = blockIdx.x;
    int tx = b % tiles, ty = (b / tiles) % tiles, m = b / (tiles * tiles);
    int i0 = ty * TO, u0 = tx * TO;
    int jr0 = i0 >> 1, jc0 = u0 >> 1;

    __shared__ float LH[TO][71];   // 18,176 B

    int tid = threadIdx.x;
    float th_h = 0.2f * (1.5f * __uint_as_float(mxh[m]));
    float th_v = 0.2f * (1.5f * __uint_as_float(mxv[m]));
    float th_d = 0.2f * (1.5f * __uint_as_float(mxd[m]));
    const float* am = a + (size_t)m * n * n;
    const float* hm = h + (size_t)m * n * n;
    const float* vm = v + (size_t)m * n * n;
    const float* dm = d + (size_t)m * n * n;

    // column idwt: 8 groups of 8 il-rows x 35 jc = 280 tasks, 2 passes each
    for (int task = tid; task < 8 * 35; task += 256) {
        int g = task / 35, jc = task % 35;
        int jcg = jc0 + jc; if (jcg > n - 1) jcg = n - 1;
#pragma unroll
        for (int pass = 0; pass < 2; ++pass) {
            int P = 2 * g + pass;               // 4-output group index
            float acc_lo[4], acc_hi[4];
#pragma unroll
            for (int k = 0; k < 4; ++k) { acc_lo[k] = 0.f; acc_hi[k] = 0.f; }
#pragma unroll
            for (int rl = 0; rl < 5; ++rl) {
                int jr = jr0 + 2 * P + rl; if (jr > n - 1) jr = n - 1;
                size_t o = (size_t)jr * n + jcg;
                float av = am[o];
                float hv = soft_enh(hm[o], th_h);
                float vv = soft_enh(vm[o], th_v);
                float dv = soft_enh(dm[o], th_d);
#pragma unroll
                for (int t = 0; t < 8; ++t) {
                    int k = 2 * rl + t - 6;      // compile-time per iteration
                    if (k >= 0 && k < 4) {
                        acc_lo[k] = fmaf(c_rec_lo[t], av, fmaf(c_rec_hi[t], hv, acc_lo[k]));
                        acc_hi[k] = fmaf(c_rec_lo[t], vv, fmaf(c_rec_hi[t], dv, acc_hi[k]));
                    }
                }
            }
#pragma unroll
            for (int k = 0; k < 4; ++k) {
                LH[4 * P + k][jc] = acc_lo[k];
                LH[4 * P + k][35 + jc] = acc_hi[k];
            }
        }
    }
    __syncthreads();

    // row idwt -> out tile
    for (int e = tid; e < TO * TO; e += 256) {
        int il = e >> 6, ul = e & 63;
        int t0 = ul & 1;
        float acc = 0.f;
#pragma unroll
        for (int s = 0; s < 4; ++s) {
            int t = t0 + 2 * s;
            int c = (ul + 6 - t) >> 1;
            acc = fmaf(c_rec_lo[t], LH[il][c], acc);
            acc = fmaf(c_rec_hi[t], LH[il][35 + c], acc);
        }
        int gi = i0 + il, gu = u0 + ul;
        if (gi < Ho && gu < Ho)
            out[((size_t)m * Ho + gi) * Ho + gu] = acc;
    }
}

extern "C" void kernel_launch(void* const* d_in, const int* in_sizes, int n_in,
                              void* d_out, int out_size, void* d_ws, size_t ws_size,
                              hipStream_t stream) {
    const float* x = (const float*)d_in[0];
    float* out = (float*)d_out;
    float* ws = (float*)d_ws;

    const int M = 96, S1 = 510, N1 = 258, N2 = 132;
    const long S_l1 = (long)M * N1 * N1;
    const long S_l2 = (long)M * N2 * N2;

    float* aa1 = ws;
    float* h1  = aa1 + S_l1;
    float* v1  = h1 + S_l1;
    float* d1  = v1 + S_l1;
    float* a1r = d1 + S_l1;
    float* a2  = a1r + S_l1;
    float* h2  = a2 + S_l2;
    float* v2  = h2 + S_l2;
    float* d2  = v2 + S_l2;
    unsigned* th = (unsigned*)(d2 + S_l2);   // 6*96 uints

    long need = 5 * S_l1 + 4 * S_l2 + 576;
    if (ws_size < (size_t)need * sizeof(float)) return;

    unsigned *th_h1 = th, *th_v1 = th + 96, *th_d1 = th + 192;
    unsigned *th_h2 = th + 288, *th_v2 = th + 384, *th_d2 = th + 480;

    hipMemsetAsync(th, 0, 576 * sizeof(unsigned), stream);

    // Level 1 decomposition: x(510) -> bands(258). 9x9 tiles per image.
    fused_dwt2_k<<<9 * 9 * M, 256, 0, stream>>>(x, S1, N1, 9, aa1, h1, v1, d1,
                                                th_h1, th_v1, th_d1);
    // Level 2 decomposition: aa1(258) -> bands(132). 5x5 tiles.
    fused_dwt2_k<<<5 * 5 * M, 256, 0, stream>>>(aa1, N1, N2, 5, a2, h2, v2, d2,
                                                th_h2, th_v2, th_d2);
    // Level 2 reconstruction: (132) -> a1r(258). 5x5 tiles of 64.
    fused_idwt2_k<<<5 * 5 * M, 256, 0, stream>>>(a2, h2, v2, d2, th_h2, th_v2, th_d2,
                                                 N2, N1, 5, a1r);
    // Level 1 reconstruction: (258) -> out(510). 8x8 tiles of 64.
    fused_idwt2_k<<<8 * 8 * M, 256, 0, stream>>>(a1r, h1, v1, d1, th_h1, th_v1, th_d1,
                                                 N1, S1, 8, out);
}